// Round 1
// baseline (2444.935 us; speedup 1.0000x reference)
//
#include <hip/hip_runtime.h>

#define BATCH 8
#define NPTS 4096
#define KSAMP 1024
#define KNEI 64
#define OUTC 131   // 3 xyz + 128 feat

// ---------------------------------------------------------------------------
// Kernel 1: farthest point sampling. One block per batch, 1024 threads,
// 4 points per thread held in registers; points mirrored to LDS for the
// random-access read of the newly selected point each iteration.
// Writes selected xyz directly into out[b][s][0..2].
// ---------------------------------------------------------------------------
__global__ __launch_bounds__(1024) void fps_kernel(const float* __restrict__ pts,
                                                   float* __restrict__ out)
{
    const int b = blockIdx.x;
    const int t = threadIdx.x;
    const float* p = pts + (size_t)b * NPTS * 3;

    __shared__ float lx[NPTS], ly[NPTS], lz[NPTS];
    __shared__ float cval[2][16];
    __shared__ int   cidx[2][16];

    float px[4], py[4], pz[4], md[4];
#pragma unroll
    for (int i = 0; i < 4; ++i) {
        int n = t + i * 1024;
        px[i] = p[n * 3 + 0];
        py[i] = p[n * 3 + 1];
        pz[i] = p[n * 3 + 2];
        lx[n] = px[i]; ly[n] = py[i]; lz[n] = pz[i];
        md[i] = 1e10f;   // reference 'big'
    }
    if (t == 0) {
        float* o = out + (size_t)b * KSAMP * OUTC;
        o[0] = p[0]; o[1] = p[1]; o[2] = p[2];   // first selected = index 0
    }
    __syncthreads();

    const int wave = t >> 6;
    const int lane = t & 63;
    int cur = 0;

    for (int s = 1; s < KSAMP; ++s) {
        const float qx = lx[cur], qy = ly[cur], qz = lz[cur];
        float bv = -1.0f;
        int   bi = 0;
#pragma unroll
        for (int i = 0; i < 4; ++i) {
            float dx = px[i] - qx, dy = py[i] - qy, dz = pz[i] - qz;
            float d = dx * dx + dy * dy + dz * dz;
            md[i] = fminf(md[i], d);
            // ascending index order within thread -> strict '>' keeps lowest
            // index on ties (jnp.argmax tie rule)
            if (md[i] > bv) { bv = md[i]; bi = t + i * 1024; }
        }
        // wave argmax butterfly (max value, lowest index on tie)
#pragma unroll
        for (int m = 1; m < 64; m <<= 1) {
            float ov = __shfl_xor(bv, m);
            int   oi = __shfl_xor(bi, m);
            if (ov > bv || (ov == bv && oi < bi)) { bv = ov; bi = oi; }
        }
        const int par = s & 1;
        if (lane == 0) { cval[par][wave] = bv; cidx[par][wave] = bi; }
        __syncthreads();
        // every thread reduces the 16 wave candidates (LDS broadcast reads)
        float wv = cval[par][0];
        int   wi = cidx[par][0];
#pragma unroll
        for (int w = 1; w < 16; ++w) {
            float v  = cval[par][w];
            int   ii = cidx[par][w];
            if (v > wv || (v == wv && ii < wi)) { wv = v; wi = ii; }
        }
        cur = wi;
        if (t == 0) {
            float* o = out + ((size_t)b * KSAMP + s) * OUTC;
            o[0] = lx[cur]; o[1] = ly[cur]; o[2] = lz[cur];
        }
    }
}

// ---------------------------------------------------------------------------
// Kernel 2: fused ball-query + 3-layer MLP + neighbor max-pool.
// One wave (block of 64) per query; lane = neighbor slot.
// Ball query: ballot/popcount compaction of first 64 in-radius points (index
// order) into a small LDS buffer; missing neighbors stay (0,0,0) like the
// reference's zero padding. MLP: fully unrolled fp32 FMA chains, h0/h1 in
// registers (static indices only), weights via uniform scalar loads.
// ---------------------------------------------------------------------------
__global__ __launch_bounds__(64) void bqmlp_kernel(
    const float* __restrict__ pts,
    const float* __restrict__ w0, const float* __restrict__ b0,
    const float* __restrict__ w1, const float* __restrict__ b1,
    const float* __restrict__ w2, const float* __restrict__ b2,
    float* __restrict__ out)
{
    const int q    = blockIdx.x;        // 0..8191
    const int b    = q >> 10;
    const int lane = threadIdx.x;
    const float* p = pts + (size_t)b * NPTS * 3;
    float* orow    = out + (size_t)q * OUTC;

    // query coords (written by fps_kernel earlier in the same stream)
    const float qx = orow[0], qy = orow[1], qz = orow[2];

    // d2 < float(0.04), replicating the reference's expanded-form arithmetic
    const float RR = 0.04f;  // fl32(0.2*0.2 in double)
    const float q2 = __fadd_rn(__fadd_rn(__fmul_rn(qx, qx), __fmul_rn(qy, qy)),
                               __fmul_rn(qz, qz));

    __shared__ float nx[KNEI], ny[KNEI], nz[KNEI];
    nx[lane] = 0.0f; ny[lane] = 0.0f; nz[lane] = 0.0f;
    __syncthreads();

    int total = 0;
    for (int c = 0; c < NPTS / 64 && total < KNEI; ++c) {
        const int n = c * 64 + lane;
        const float x = p[n * 3 + 0];
        const float y = p[n * 3 + 1];
        const float z = p[n * 3 + 2];
        const float p2  = __fadd_rn(__fadd_rn(__fmul_rn(x, x), __fmul_rn(y, y)),
                                    __fmul_rn(z, z));
        const float dot = __fadd_rn(__fadd_rn(__fmul_rn(qx, x), __fmul_rn(qy, y)),
                                    __fmul_rn(qz, z));
        const float d2  = __fsub_rn(__fadd_rn(q2, p2), __fmul_rn(2.0f, dot));
        const bool valid = d2 < RR;
        const unsigned long long mask = __ballot(valid);
        const int pos = total + (int)__popcll(mask & ((1ull << lane) - 1ull));
        if (valid && pos < KNEI) { nx[pos] = x; ny[pos] = y; nz[pos] = z; }
        total += (int)__popcll(mask);
    }
    __syncthreads();   // block == one wave: cheap, and orders the LDS writes

    const float x = nx[lane], y = ny[lane], z = nz[lane];

    // ---- layer 1: 3 -> 64 ----
    float h0[64];
#pragma unroll
    for (int j = 0; j < 64; ++j) {
        float a = fmaf(x, w0[j], fmaf(y, w0[64 + j], fmaf(z, w0[128 + j], b0[j])));
        h0[j] = fmaxf(a, 0.0f);
    }

    // ---- layer 2: 64 -> 64 ----
    float h1[64];
#pragma unroll
    for (int jb = 0; jb < 4; ++jb) {
        float acc[16];
#pragma unroll
        for (int i = 0; i < 16; ++i) acc[i] = b1[jb * 16 + i];
#pragma unroll
        for (int k = 0; k < 64; ++k) {
#pragma unroll
            for (int i = 0; i < 16; ++i)
                acc[i] = fmaf(h0[k], w1[k * 64 + jb * 16 + i], acc[i]);
        }
#pragma unroll
        for (int i = 0; i < 16; ++i) h1[jb * 16 + i] = fmaxf(acc[i], 0.0f);
    }

    // ---- layer 3: 64 -> 128, fused relu + cross-lane (neighbor) max ----
#pragma unroll
    for (int jb = 0; jb < 8; ++jb) {
        float acc[16];
#pragma unroll
        for (int i = 0; i < 16; ++i) acc[i] = b2[jb * 16 + i];
#pragma unroll
        for (int k = 0; k < 64; ++k) {
#pragma unroll
            for (int i = 0; i < 16; ++i)
                acc[i] = fmaf(h1[k], w2[k * 128 + jb * 16 + i], acc[i]);
        }
#pragma unroll
        for (int i = 0; i < 16; ++i) {
            float v = fmaxf(acc[i], 0.0f);
#pragma unroll
            for (int m = 1; m < 64; m <<= 1)
                v = fmaxf(v, __shfl_xor(v, m));
            acc[i] = v;
        }
        if (lane == 0) {
#pragma unroll
            for (int i = 0; i < 16; ++i) orow[3 + jb * 16 + i] = acc[i];
        }
    }
}

extern "C" void kernel_launch(void* const* d_in, const int* in_sizes, int n_in,
                              void* d_out, int out_size, void* d_ws, size_t ws_size,
                              hipStream_t stream)
{
    (void)in_sizes; (void)n_in; (void)out_size; (void)d_ws; (void)ws_size;
    const float* pts = (const float*)d_in[0];
    const float* w0  = (const float*)d_in[1];
    const float* b0  = (const float*)d_in[2];
    const float* w1  = (const float*)d_in[3];
    const float* b1  = (const float*)d_in[4];
    const float* w2  = (const float*)d_in[5];
    const float* b2  = (const float*)d_in[6];
    float* out = (float*)d_out;

    hipLaunchKernelGGL(fps_kernel, dim3(BATCH), dim3(1024), 0, stream, pts, out);
    hipLaunchKernelGGL(bqmlp_kernel, dim3(BATCH * KSAMP), dim3(64), 0, stream,
                       pts, w0, b0, w1, b1, w2, b2, out);
}

// Round 2
// 974.105 us; speedup vs baseline: 2.5099x; 2.5099x over previous
//
#include <hip/hip_runtime.h>

#define BATCH 8
#define NPTS 4096
#define KSAMP 1024
#define KNEI 64
#define OUTC 131   // 3 xyz + 128 feat

// ---------------------------------------------------------------------------
// DPP helpers: wave64 max-reduction, result valid in lane 63.
// row_shr:1/2/4/8 then row_bcast15, row_bcast31 (classic GCN sequence).
// bound_ctrl=true -> out-of-bounds lanes read 0, which is the identity for
// max over non-negative values (all our uses are nonneg).
// ---------------------------------------------------------------------------
__device__ __forceinline__ unsigned long long umax64(unsigned long long a,
                                                     unsigned long long b)
{
    return a > b ? a : b;
}

#define DPP_U64_STEP(v, CTRL)                                                  \
    {                                                                          \
        int _lo = __builtin_amdgcn_update_dpp(0, (int)(unsigned)(v), (CTRL),   \
                                              0xF, 0xF, true);                 \
        int _hi = __builtin_amdgcn_update_dpp(0, (int)((v) >> 32), (CTRL),     \
                                              0xF, 0xF, true);                 \
        unsigned long long _o =                                                \
            ((unsigned long long)(unsigned)_hi << 32) | (unsigned)_lo;         \
        (v) = umax64((v), _o);                                                 \
    }

__device__ __forceinline__ unsigned long long wave_umax64(unsigned long long v)
{
    DPP_U64_STEP(v, 0x111)  // row_shr:1
    DPP_U64_STEP(v, 0x112)  // row_shr:2
    DPP_U64_STEP(v, 0x114)  // row_shr:4
    DPP_U64_STEP(v, 0x118)  // row_shr:8
    DPP_U64_STEP(v, 0x142)  // row_bcast:15
    DPP_U64_STEP(v, 0x143)  // row_bcast:31
    return v;               // lane 63 holds the wave max
}

#define DPP_F32MAX_STEP(v, CTRL)                                               \
    {                                                                          \
        int _s = __builtin_amdgcn_update_dpp(0, __float_as_int(v), (CTRL),     \
                                             0xF, 0xF, true);                  \
        (v) = fmaxf((v), __int_as_float(_s));                                  \
    }

__device__ __forceinline__ float wave_fmax_nonneg(float v)
{
    DPP_F32MAX_STEP(v, 0x111)
    DPP_F32MAX_STEP(v, 0x112)
    DPP_F32MAX_STEP(v, 0x114)
    DPP_F32MAX_STEP(v, 0x118)
    DPP_F32MAX_STEP(v, 0x142)
    DPP_F32MAX_STEP(v, 0x143)
    return v;               // lane 63 holds the wave max
}

// ---------------------------------------------------------------------------
// Kernel 1: farthest point sampling. One block of 256 threads per batch
// (1 wave per SIMD -> no intra-SIMD wave serialization). 16 points/thread in
// registers; points mirrored in LDS for the random-access broadcast read of
// the current query. Candidate = packed u64 (dist bits << 32 | (4095-idx)):
// nonneg float bits compare as ints, and ties resolve to the LOWEST index,
// exactly matching jnp.argmax. Wave reduce is DPP (VALU latency), cross-wave
// is 4 LDS slots + one parity-double-buffered barrier per iteration.
// Distance arithmetic is kept textually identical to the previously verified
// kernel so argmax picks cannot flip.
// ---------------------------------------------------------------------------
#define FPS_T 256
#define FPS_PPT 16

__global__ __launch_bounds__(FPS_T) void fps_kernel(const float* __restrict__ pts,
                                                    float* __restrict__ out)
{
    const int b = blockIdx.x;
    const int t = threadIdx.x;
    const float* p = pts + (size_t)b * NPTS * 3;

    __shared__ float lx[NPTS], ly[NPTS], lz[NPTS];
    __shared__ unsigned long long cand[2][4];

    float px[FPS_PPT], py[FPS_PPT], pz[FPS_PPT], md[FPS_PPT];
#pragma unroll
    for (int i = 0; i < FPS_PPT; ++i) {
        const int n = t * FPS_PPT + i;   // thread-contiguous: vectorizable init
        px[i] = p[n * 3 + 0];
        py[i] = p[n * 3 + 1];
        pz[i] = p[n * 3 + 2];
        lx[n] = px[i]; ly[n] = py[i]; lz[n] = pz[i];
        md[i] = 1e10f;                   // reference 'big'
    }
    if (t == 0) {
        float* o = out + (size_t)b * KSAMP * OUTC;
        o[0] = p[0]; o[1] = p[1]; o[2] = p[2];   // first selected = index 0
    }
    __syncthreads();

    const int wave = t >> 6;
    const int lane = t & 63;
    int cur = 0;

    for (int s = 1; s < KSAMP; ++s) {
        const float qx = lx[cur], qy = ly[cur], qz = lz[cur];

        // update min-dists (same arithmetic as the verified kernel)
#pragma unroll
        for (int i = 0; i < FPS_PPT; ++i) {
            float dx = px[i] - qx, dy = py[i] - qy, dz = pz[i] - qz;
            float d = dx * dx + dy * dy + dz * dz;
            md[i] = fminf(md[i], d);
        }

        // thread-local tree argmax over 16 packed candidates (all static idx)
        unsigned long long c[FPS_PPT];
#pragma unroll
        for (int i = 0; i < FPS_PPT; ++i)
            c[i] = ((unsigned long long)__float_as_uint(md[i]) << 32)
                 | (unsigned)(4095 - (t * FPS_PPT + i));
#pragma unroll
        for (int i = 0; i < 8; ++i) c[i] = umax64(c[i], c[i + 8]);
#pragma unroll
        for (int i = 0; i < 4; ++i) c[i] = umax64(c[i], c[i + 4]);
        c[0] = umax64(c[0], c[2]);
        c[1] = umax64(c[1], c[3]);
        unsigned long long best = umax64(c[0], c[1]);

        // wave reduce (DPP, result in lane 63), then cross-wave via LDS
        best = wave_umax64(best);
        const int par = s & 1;
        if (lane == 63) cand[par][wave] = best;
        __syncthreads();

        unsigned long long g = umax64(umax64(cand[par][0], cand[par][1]),
                                      umax64(cand[par][2], cand[par][3]));
        cur = 4095 - (int)(g & 0xffffffffu);

        if (t == 0) {
            float* o = out + ((size_t)b * KSAMP + s) * OUTC;
            o[0] = lx[cur]; o[1] = ly[cur]; o[2] = lz[cur];
        }
    }
}

// ---------------------------------------------------------------------------
// Kernel 2: fused ball-query + 3-layer MLP + neighbor max-pool.
// One wave (block of 64) per query; lane = neighbor slot. Unchanged from the
// verified kernel except the final cross-lane max: DPP chain instead of 6
// ds_bpermute shuffles per value (768 of them), store from lane 63.
// ---------------------------------------------------------------------------
__global__ __launch_bounds__(64) void bqmlp_kernel(
    const float* __restrict__ pts,
    const float* __restrict__ w0, const float* __restrict__ b0,
    const float* __restrict__ w1, const float* __restrict__ b1,
    const float* __restrict__ w2, const float* __restrict__ b2,
    float* __restrict__ out)
{
    const int q    = blockIdx.x;        // 0..8191
    const int b    = q >> 10;
    const int lane = threadIdx.x;
    const float* p = pts + (size_t)b * NPTS * 3;
    float* orow    = out + (size_t)q * OUTC;

    // query coords (written by fps_kernel earlier in the same stream)
    const float qx = orow[0], qy = orow[1], qz = orow[2];

    // d2 < float(0.04), replicating the reference's expanded-form arithmetic
    const float RR = 0.04f;
    const float q2 = __fadd_rn(__fadd_rn(__fmul_rn(qx, qx), __fmul_rn(qy, qy)),
                               __fmul_rn(qz, qz));

    __shared__ float nx[KNEI], ny[KNEI], nz[KNEI];
    nx[lane] = 0.0f; ny[lane] = 0.0f; nz[lane] = 0.0f;
    __syncthreads();

    int total = 0;
    for (int c = 0; c < NPTS / 64 && total < KNEI; ++c) {
        const int n = c * 64 + lane;
        const float x = p[n * 3 + 0];
        const float y = p[n * 3 + 1];
        const float z = p[n * 3 + 2];
        const float p2  = __fadd_rn(__fadd_rn(__fmul_rn(x, x), __fmul_rn(y, y)),
                                    __fmul_rn(z, z));
        const float dot = __fadd_rn(__fadd_rn(__fmul_rn(qx, x), __fmul_rn(qy, y)),
                                    __fmul_rn(qz, z));
        const float d2  = __fsub_rn(__fadd_rn(q2, p2), __fmul_rn(2.0f, dot));
        const bool valid = d2 < RR;
        const unsigned long long mask = __ballot(valid);
        const int pos = total + (int)__popcll(mask & ((1ull << lane) - 1ull));
        if (valid && pos < KNEI) { nx[pos] = x; ny[pos] = y; nz[pos] = z; }
        total += (int)__popcll(mask);
    }
    __syncthreads();   // block == one wave: cheap, and orders the LDS writes

    const float x = nx[lane], y = ny[lane], z = nz[lane];

    // ---- layer 1: 3 -> 64 ----
    float h0[64];
#pragma unroll
    for (int j = 0; j < 64; ++j) {
        float a = fmaf(x, w0[j], fmaf(y, w0[64 + j], fmaf(z, w0[128 + j], b0[j])));
        h0[j] = fmaxf(a, 0.0f);
    }

    // ---- layer 2: 64 -> 64 ----
    float h1[64];
#pragma unroll
    for (int jb = 0; jb < 4; ++jb) {
        float acc[16];
#pragma unroll
        for (int i = 0; i < 16; ++i) acc[i] = b1[jb * 16 + i];
#pragma unroll
        for (int k = 0; k < 64; ++k) {
#pragma unroll
            for (int i = 0; i < 16; ++i)
                acc[i] = fmaf(h0[k], w1[k * 64 + jb * 16 + i], acc[i]);
        }
#pragma unroll
        for (int i = 0; i < 16; ++i) h1[jb * 16 + i] = fmaxf(acc[i], 0.0f);
    }

    // ---- layer 3: 64 -> 128, fused relu + cross-lane (neighbor) max ----
#pragma unroll
    for (int jb = 0; jb < 8; ++jb) {
        float acc[16];
#pragma unroll
        for (int i = 0; i < 16; ++i) acc[i] = b2[jb * 16 + i];
#pragma unroll
        for (int k = 0; k < 64; ++k) {
#pragma unroll
            for (int i = 0; i < 16; ++i)
                acc[i] = fmaf(h1[k], w2[k * 128 + jb * 16 + i], acc[i]);
        }
#pragma unroll
        for (int i = 0; i < 16; ++i) {
            float v = fmaxf(acc[i], 0.0f);   // relu before pooling
            acc[i] = wave_fmax_nonneg(v);    // valid in lane 63
        }
        if (lane == 63) {
#pragma unroll
            for (int i = 0; i < 16; ++i) orow[3 + jb * 16 + i] = acc[i];
        }
    }
}

extern "C" void kernel_launch(void* const* d_in, const int* in_sizes, int n_in,
                              void* d_out, int out_size, void* d_ws, size_t ws_size,
                              hipStream_t stream)
{
    (void)in_sizes; (void)n_in; (void)out_size; (void)d_ws; (void)ws_size;
    const float* pts = (const float*)d_in[0];
    const float* w0  = (const float*)d_in[1];
    const float* b0  = (const float*)d_in[2];
    const float* w1  = (const float*)d_in[3];
    const float* b1  = (const float*)d_in[4];
    const float* w2  = (const float*)d_in[5];
    const float* b2  = (const float*)d_in[6];
    float* out = (float*)d_out;

    hipLaunchKernelGGL(fps_kernel, dim3(BATCH), dim3(FPS_T), 0, stream, pts, out);
    hipLaunchKernelGGL(bqmlp_kernel, dim3(BATCH * KSAMP), dim3(64), 0, stream,
                       pts, w0, b0, w1, b1, w2, b2, out);
}